// Round 6
// baseline (370.834 us; speedup 1.0000x reference)
//
#include <hip/hip_runtime.h>
#include <hip/hip_bf16.h>

#define HH 100
#define WW 352
#define NB 2
#define LL 5
#define NN 10
#define CCH 64
#define HW (HH*WW)
#define KTOP (HW/4)
#define HP (HH+6)
#define WP 390   // 6*64 + 6, covers conv reads for padded W tiles

typedef __bf16 bf16x8 __attribute__((ext_vector_type(8)));
typedef float f32x4 __attribute__((ext_vector_type(4)));

// ws layout (bytes), 16B aligned
#define WS_CONF   0u
#define WS_TAU    1408000u
#define WS_WTP    1408064u
#define WS_PAD    1809472u
#define WS_GHIST  12392512u
#define WS_XT     13047872u
#define PAD_BYTES    ((size_t)NB*HP*WP*CCH*2)        // 10,583,040
#define MEMSET_BYTES (10583040u + (unsigned)NN*16384u*4u)  // pad + ghist

__device__ __forceinline__ void load_theta(const float* __restrict__ ptm, int b, int l, float th[6]) {
#pragma clang fp contract(off)
  const float* tb = ptm + ((b*LL + 0)*LL + l)*16;  // pairwise_t_matrix[b,0,l,:,:]
  th[0] = tb[0] * 1.0f;
  th[1] = tb[1] * (float)(100.0/352.0);
  th[2] = tb[3] * (float)(2.0/(2.0*0.4*352.0));
  th[3] = tb[4] * (float)(352.0/100.0);
  th[4] = tb[5] * 1.0f;
  th[5] = tb[7] * (float)(2.0/(2.0*0.4*100.0));
}

// --- Kernel 1: conf_w = bilinear-warp of sigmoid(max(psm[n,0],psm[n,1])) ---
__global__ void conf_warp_kernel(const float* __restrict__ psm,
                                 const float* __restrict__ ptm,
                                 float* __restrict__ conf_w) {
#pragma clang fp contract(off)
  int w = blockIdx.x * 128 + threadIdx.x;
  int h = blockIdx.y;
  int n = blockIdx.z;
  if (w >= WW) return;
  int b = n / LL, l = n % LL;
  float th[6];
  load_theta(ptm, b, l, th);
  float gy = ((float)h + 0.5f) * (float)(2.0/100.0) - 1.0f;
  float gx = ((float)w + 0.5f) * (float)(2.0/352.0) - 1.0f;
  float sx = th[0]*gx + th[1]*gy + th[2];
  float sy = th[3]*gx + th[4]*gy + th[5];
  float px = (sx + 1.0f) * ((float)WW * 0.5f) - 0.5f;
  float py = (sy + 1.0f) * ((float)HH * 0.5f) - 0.5f;
  float x0 = floorf(px), y0 = floorf(py);
  float wx1 = px - x0, wx0 = 1.0f - wx1;
  float wy1 = py - y0, wy0 = 1.0f - wy1;
  const float* p0 = psm + (size_t)(n*2 + 0)*HW;
  const float* p1 = psm + (size_t)(n*2 + 1)*HW;
  float yy[2] = {y0, y0 + 1.0f};
  float xx[2] = {x0, x0 + 1.0f};
  float wgt[2][2] = {{wy0*wx0, wy0*wx1}, {wy1*wx0, wy1*wx1}};
  float out = 0.0f;
  for (int iy = 0; iy < 2; ++iy) {
    for (int ix = 0; ix < 2; ++ix) {
      float yv = yy[iy], xv = xx[ix];
      float yc = fminf(fmaxf(yv, 0.0f), (float)(HH-1));
      float xc = fminf(fmaxf(xv, 0.0f), (float)(WW-1));
      int yi = (int)yc, xi = (int)xc;
      int idx = yi*WW + xi;
      float m = fmaxf(p0[idx], p1[idx]);
      float v = 1.0f / (1.0f + expf(-m));
      bool valid = (yv >= 0.0f) && (yv <= (float)(HH-1)) && (xv >= 0.0f) && (xv <= (float)(WW-1));
      out += (valid ? v : 0.0f) * wgt[iy][ix];
    }
  }
  conf_w[(size_t)n*HW + h*WW + w] = out;
}

// inclusive block scan over 256 threads (thread order = descending bins)
__device__ __forceinline__ unsigned int scan_incl(unsigned int v, int lane, int wid,
                                                  volatile unsigned int* wsum) {
  unsigned int inc = v;
  for (int off = 1; off < 64; off <<= 1) {
    unsigned int o = __shfl_up(inc, off);
    if (lane >= off) inc += o;
  }
  if (lane == 63) wsum[wid] = inc;
  __syncthreads();
  unsigned int wadd = 0;
  for (int w2 = 0; w2 < wid; ++w2) wadd += wsum[w2];
  return inc + wadd;
}

// --- Kernel 2a: distributed 14-bit (u>>18) histogram: 16 slices/image -> global hist ---
__global__ __launch_bounds__(256) void topk_hist_kernel(const float* __restrict__ conf_w,
                                                        unsigned int* __restrict__ ghist) {
  __shared__ unsigned int hist[16384];
  int n = blockIdx.y, slice = blockIdx.x;
  int tid = threadIdx.x;
  for (int i = tid; i < 16384; i += 256) hist[i] = 0u;
  __syncthreads();
  const float4* src = (const float4*)(conf_w + (size_t)n*HW);
  int lo = slice*550, hi = lo + 550;   // 16*550 = 8800 = HW/4
  for (int i = lo + tid; i < hi; i += 256) {
    float4 v = src[i];
    atomicAdd(&hist[__float_as_uint(v.x) >> 18], 1u);
    atomicAdd(&hist[__float_as_uint(v.y) >> 18], 1u);
    atomicAdd(&hist[__float_as_uint(v.z) >> 18], 1u);
    atomicAdd(&hist[__float_as_uint(v.w) >> 18], 1u);
  }
  __syncthreads();
  unsigned int* gh = ghist + (size_t)n*16384;
  for (int i = tid; i < 16384; i += 256) {
    unsigned int v = hist[i];
    if (v) atomicAdd(&gh[i], v);
  }
}

// --- Kernel 2b: per-image select: round1 from global hist, rounds 2 (14b) & 3 (4b) by rescan ---
__global__ __launch_bounds__(256) void topk_select_kernel(const float* __restrict__ conf_w,
                                                          const unsigned int* __restrict__ ghist,
                                                          float* __restrict__ tau) {
  __shared__ unsigned int hist[16384];
  __shared__ unsigned int wsum[4];
  __shared__ unsigned int s_pref, s_k;
  int n = blockIdx.x;
  int tid = threadIdx.x, lane = tid & 63, wid = tid >> 6;
  const float4* src = (const float4*)(conf_w + (size_t)n*HW);
  const unsigned int* gh = ghist + (size_t)n*16384;
  // ---- round 1: top-14 bits from precomputed global hist ----
  {
    unsigned int k = KTOP;
    int top = 16383 - tid*64;
    unsigned int csum = 0u;
    for (int i = 0; i < 64; ++i) csum += gh[top - i];
    unsigned int incl = scan_incl(csum, lane, wid, wsum);
    unsigned int excl = incl - csum;
    if (excl < k && incl >= k) {
      unsigned int run = excl;
      for (int i = 0; i < 64; ++i) {
        unsigned int c = gh[top - i];
        if (run + c >= k) { s_pref = (unsigned int)(top - i); s_k = k - run; break; }
        run += c;
      }
    }
    __syncthreads();
  }
  // ---- round 2: next 14 bits, rescan with prefix filter ----
  unsigned int pref14 = s_pref, k2 = s_k;
  for (int i = tid; i < 16384; i += 256) hist[i] = 0u;
  __syncthreads();
  for (int i = tid; i < HW/4; i += 256) {
    float4 v = src[i];
    unsigned int u0 = __float_as_uint(v.x);
    unsigned int u1 = __float_as_uint(v.y);
    unsigned int u2 = __float_as_uint(v.z);
    unsigned int u3 = __float_as_uint(v.w);
    if ((u0 >> 18) == pref14) atomicAdd(&hist[(u0 >> 4) & 16383u], 1u);
    if ((u1 >> 18) == pref14) atomicAdd(&hist[(u1 >> 4) & 16383u], 1u);
    if ((u2 >> 18) == pref14) atomicAdd(&hist[(u2 >> 4) & 16383u], 1u);
    if ((u3 >> 18) == pref14) atomicAdd(&hist[(u3 >> 4) & 16383u], 1u);
  }
  __syncthreads();
  {
    int top = 16383 - tid*64;
    unsigned int csum = 0u;
    for (int i = 0; i < 64; ++i) csum += hist[top - i];
    unsigned int incl = scan_incl(csum, lane, wid, wsum);
    unsigned int excl = incl - csum;
    if (excl < k2 && incl >= k2) {
      unsigned int run = excl;
      for (int i = 0; i < 64; ++i) {
        unsigned int c = hist[top - i];
        if (run + c >= k2) { s_pref = (pref14 << 14) | (unsigned int)(top - i); s_k = k2 - run; break; }
        run += c;
      }
    }
    __syncthreads();
  }
  // ---- round 3: low 4 bits ----
  unsigned int pref28 = s_pref, k3 = s_k;
  if (tid < 16) hist[tid] = 0u;
  __syncthreads();
  for (int i = tid; i < HW/4; i += 256) {
    float4 v = src[i];
    unsigned int u0 = __float_as_uint(v.x);
    unsigned int u1 = __float_as_uint(v.y);
    unsigned int u2 = __float_as_uint(v.z);
    unsigned int u3 = __float_as_uint(v.w);
    if ((u0 >> 4) == pref28) atomicAdd(&hist[u0 & 15u], 1u);
    if ((u1 >> 4) == pref28) atomicAdd(&hist[u1 & 15u], 1u);
    if ((u2 >> 4) == pref28) atomicAdd(&hist[u2 & 15u], 1u);
    if ((u3 >> 4) == pref28) atomicAdd(&hist[u3 & 15u], 1u);
  }
  __syncthreads();
  if (tid == 0) {
    unsigned int run = 0u;
    for (int bb = 15; bb >= 0; --bb) {
      unsigned int c = hist[bb];
      if (run + c >= k3) { tau[n] = __uint_as_float((pref28 << 4) | (unsigned int)bb); break; }
      run += c;
    }
  }
}

// --- Kernel 3: weights fuse_w[k][c][dy][dx] -> wtp[(dy*7+dx)*64 + k][c] bf16 ---
__global__ void pack_w_kernel(const float* __restrict__ fw, __bf16* __restrict__ wtp) {
  int idx = blockIdx.x*256 + threadIdx.x;
  if (idx >= CCH*CCH*49) return;
  int c = idx & 63;
  int k = (idx >> 6) & 63;
  int dydx = idx >> 12;
  wtp[((size_t)dydx*CCH + k)*CCH + c] = (__bf16)fw[((size_t)k*CCH + c)*49 + dydx];
}

// --- Kernel 3b: x (N,C,H,W) f32 -> xT (N,H*W,C) bf16 via LDS transpose ---
__global__ __launch_bounds__(256) void repack_x_kernel(const float* __restrict__ x,
                                                       __bf16* __restrict__ xT) {
  __shared__ float tile[64][65];
  int n = blockIdx.y;
  int px0 = blockIdx.x * 64;
  int tid = threadIdx.x;
  int pxl = tid & 63;
  int c0 = tid >> 6;       // 0..3
  const float* xs = x + (size_t)n*CCH*HW + px0 + pxl;
#pragma unroll
  for (int i = 0; i < 16; ++i) {
    int c = c0 + i*4;
    tile[c][pxl] = xs[(size_t)c*HW];
  }
  __syncthreads();
  int px2 = tid >> 2;            // 0..63
  int cc0 = (tid & 3) * 16;      // 0,16,32,48
  __bf16 vv[16];
#pragma unroll
  for (int j = 0; j < 16; ++j) vv[j] = (__bf16)tile[cc0 + j][px2];
  __bf16* dst = xT + ((size_t)n*HW + px0 + px2)*CCH + cc0;
  *reinterpret_cast<bf16x8*>(dst)     = *reinterpret_cast<bf16x8*>(&vv[0]);
  *reinterpret_cast<bf16x8*>(dst + 8) = *reinterpret_cast<bf16x8*>(&vv[8]);
}

// --- Kernel 4: fused warp + mask + mean over L; thread = (pixel, channel-half) ---
__global__ __launch_bounds__(256) void warp_avg_kernel(
    const __bf16* __restrict__ xT, const float* __restrict__ ptm,
    const float* __restrict__ conf_w, const float* __restrict__ tau,
    __bf16* __restrict__ pad) {
  int t = blockIdx.x*256 + threadIdx.x;   // 0..140799
  int px = t >> 1, chh = t & 1;
  int b = (px >= HW) ? 1 : 0;
  int rem = px - b*HW;
  int h = rem / WW;
  int w = rem - h*WW;
  float acc[32];
#pragma unroll
  for (int i = 0; i < 32; ++i) acc[i] = 0.0f;
  float gy = ((float)h + 0.5f) * (float)(2.0/100.0) - 1.0f;
  float gx = ((float)w + 0.5f) * (float)(2.0/352.0) - 1.0f;
  for (int l = 0; l < LL; ++l) {
    int n = b*LL + l;
    if (l != 0 && !(conf_w[(size_t)n*HW + rem] >= tau[n])) continue;
    float th[6];
    load_theta(ptm, b, l, th);
    float sx = th[0]*gx + th[1]*gy + th[2];
    float sy = th[3]*gx + th[4]*gy + th[5];
    float fpx = (sx + 1.0f) * ((float)WW*0.5f) - 0.5f;
    float fpy = (sy + 1.0f) * ((float)HH*0.5f) - 0.5f;
    float x0 = floorf(fpx), y0 = floorf(fpy);
    float wx1 = fpx - x0, wx0 = 1.0f - wx1;
    float wy1 = fpy - y0, wy0 = 1.0f - wy1;
    float y1 = y0 + 1.0f, x1 = x0 + 1.0f;
    bool vy0 = (y0 >= 0.0f) && (y0 <= (float)(HH-1));
    bool vy1 = (y1 >= 0.0f) && (y1 <= (float)(HH-1));
    bool vx0 = (x0 >= 0.0f) && (x0 <= (float)(WW-1));
    bool vx1 = (x1 >= 0.0f) && (x1 <= (float)(WW-1));
    int yi0 = (int)fminf(fmaxf(y0, 0.0f), (float)(HH-1));
    int yi1 = (int)fminf(fmaxf(y1, 0.0f), (float)(HH-1));
    int xi0 = (int)fminf(fmaxf(x0, 0.0f), (float)(WW-1));
    int xi1 = (int)fminf(fmaxf(x1, 0.0f), (float)(WW-1));
    float wgt[4] = { wy0*wx0 * ((vy0 && vx0) ? 1.0f : 0.0f),
                     wy0*wx1 * ((vy0 && vx1) ? 1.0f : 0.0f),
                     wy1*wx0 * ((vy1 && vx0) ? 1.0f : 0.0f),
                     wy1*wx1 * ((vy1 && vx1) ? 1.0f : 0.0f) };
    int off[4] = { yi0*WW + xi0, yi0*WW + xi1, yi1*WW + xi0, yi1*WW + xi1 };
#pragma unroll
    for (int t4 = 0; t4 < 4; ++t4) {
      if (wgt[t4] == 0.0f) continue;
      float wt = wgt[t4];
      const __bf16* src = xT + ((size_t)n*HW + off[t4])*CCH + chh*32;
#pragma unroll
      for (int ch = 0; ch < 4; ++ch) {
        bf16x8 v = *reinterpret_cast<const bf16x8*>(src + ch*8);
#pragma unroll
        for (int e = 0; e < 8; ++e) acc[ch*8 + e] += wt * (float)v[e];
      }
    }
  }
  __bf16* dst = pad + (((size_t)b*HP + (h+3))*WP + (w+3))*CCH + chh*32;
#pragma unroll
  for (int ch = 0; ch < 4; ++ch) {
    bf16x8 o;
#pragma unroll
    for (int e = 0; e < 8; ++e) o[e] = (__bf16)(acc[ch*8 + e]*0.2f);
    *reinterpret_cast<bf16x8*>(dst + ch*8) = o;
  }
}

// --- Kernel 5: 7x7 conv implicit GEMM. Block: 4 waves = 2 rows x 2 khalf; wave = 64px x 32kout. ---
__global__ __launch_bounds__(256, 2) void conv_kernel(
    const __bf16* __restrict__ pad, const __bf16* __restrict__ wtp,
    const float* __restrict__ fb, float* __restrict__ out) {
  __shared__ __align__(16) __bf16 wlds[7*64*64];  // 57344 B: [dx][k][c], chunk-rotated
  int tid = threadIdx.x;
  int wave = tid >> 6, lane = tid & 63;
  int quad = lane >> 4, l16 = lane & 15;
  int r = wave & 1, khalf = wave >> 1;
  int b = blockIdx.z;
  int h = blockIdx.y*2 + r;
  int w0 = blockIdx.x*64;
  f32x4 acc[2][4];
#pragma unroll
  for (int m = 0; m < 2; ++m)
#pragma unroll
    for (int n = 0; n < 4; ++n) acc[m][n] = (f32x4){0.f,0.f,0.f,0.f};
  const __bf16* prow = pad + (((size_t)b*HP + h)*WP + w0 + l16)*CCH + quad*8;
  int r8 = lane >> 3, jc = lane & 7;
  int jcr = (jc - r8) & 7;
  int cj0 = (quad + l16) & 7;        // kc=0 (row%8 == l16%8, khalf*32 & m*16 are 0 mod 8)
  int cj1 = (quad + 4 + l16) & 7;    // kc=1
#pragma unroll 1
  for (int dy = 0; dy < 7; ++dy) {
    if (dy) __syncthreads();
    const __bf16* wdy = wtp + dy*28672;
#pragma unroll
    for (int j = 0; j < 14; ++j) {
      int q = wave*14 + j;
      int R = q*8 + r8;
      int jp = (jcr - q*8) & 7;
      bf16x8 v = *reinterpret_cast<const bf16x8*>(wdy + R*64 + jp*8);
      *reinterpret_cast<bf16x8*>(&wlds[q*512 + r8*64 + jc*8]) = v;
    }
    bf16x8 bfr[2][4][2];
#pragma unroll
    for (int n = 0; n < 4; ++n)
#pragma unroll
      for (int kc = 0; kc < 2; ++kc)
        bfr[0][n][kc] = *reinterpret_cast<const bf16x8*>(prow + ((size_t)dy*WP + n*16)*CCH + kc*32);
    __syncthreads();
#pragma unroll
    for (int dx = 0; dx < 7; ++dx) {
      int cur = dx & 1, nxt = cur ^ 1;
      if (dx < 6) {
#pragma unroll
        for (int n = 0; n < 4; ++n)
#pragma unroll
          for (int kc = 0; kc < 2; ++kc)
            bfr[nxt][n][kc] = *reinterpret_cast<const bf16x8*>(prow + ((size_t)dy*WP + dx + 1 + n*16)*CCH + kc*32);
      }
      bf16x8 af[2][2];
#pragma unroll
      for (int m = 0; m < 2; ++m) {
        int row = dx*64 + khalf*32 + m*16 + l16;
        af[m][0] = *reinterpret_cast<const bf16x8*>(&wlds[row*64 + cj0*8]);
        af[m][1] = *reinterpret_cast<const bf16x8*>(&wlds[row*64 + cj1*8]);
      }
#pragma unroll
      for (int kc = 0; kc < 2; ++kc)
#pragma unroll
        for (int m = 0; m < 2; ++m)
#pragma unroll
          for (int n = 0; n < 4; ++n)
            acc[m][n] = __builtin_amdgcn_mfma_f32_16x16x32_bf16(af[m][kc], bfr[cur][n][kc], acc[m][n], 0, 0, 0);
    }
  }
#pragma unroll
  for (int n = 0; n < 4; ++n) {
    int wpix = w0 + n*16 + l16;
    if (wpix < WW) {
#pragma unroll
      for (int m = 0; m < 2; ++m) {
#pragma unroll
        for (int rr = 0; rr < 4; ++rr) {
          int kg = khalf*32 + m*16 + quad*4 + rr;
          out[((size_t)(b*CCH + kg)*HH + h)*WW + wpix] = acc[m][n][rr] + fb[kg];
        }
      }
    }
  }
}

extern "C" void kernel_launch(void* const* d_in, const int* in_sizes, int n_in,
                              void* d_out, int out_size, void* d_ws, size_t ws_size,
                              hipStream_t stream) {
  (void)in_sizes; (void)n_in; (void)out_size; (void)ws_size;
  const float* x   = (const float*)d_in[0];
  const float* psm = (const float*)d_in[1];
  // d_in[2] = record_len (unused by reference)
  const float* ptm = (const float*)d_in[3];
  const float* fw  = (const float*)d_in[4];
  const float* fb  = (const float*)d_in[5];
  float* out = (float*)d_out;
  char* ws = (char*)d_ws;
  float*        conf  = (float*)(ws + WS_CONF);
  float*        tau   = (float*)(ws + WS_TAU);
  __bf16*       wtp   = (__bf16*)(ws + WS_WTP);
  __bf16*       pad   = (__bf16*)(ws + WS_PAD);
  unsigned int* ghist = (unsigned int*)(ws + WS_GHIST);
  __bf16*       xT    = (__bf16*)(ws + WS_XT);

  hipMemsetAsync(ws + WS_PAD, 0, MEMSET_BYTES, stream);  // pad halo + ghist
  conf_warp_kernel<<<dim3(3, HH, NN), 128, 0, stream>>>(psm, ptm, conf);
  pack_w_kernel<<<(CCH*CCH*49 + 255)/256, 256, 0, stream>>>(fw, wtp);
  repack_x_kernel<<<dim3(HW/64, NN), 256, 0, stream>>>(x, xT);
  topk_hist_kernel<<<dim3(16, NN), 256, 0, stream>>>(conf, ghist);
  topk_select_kernel<<<NN, 256, 0, stream>>>(conf, ghist, tau);
  warp_avg_kernel<<<dim3(NB*HW*2/256), 256, 0, stream>>>(xT, ptm, conf, tau, pad);
  conv_kernel<<<dim3(6, 50, NB), 256, 0, stream>>>(pad, wtp, fb, out);
}